// Round 7
// baseline (219.550 us; speedup 1.0000x reference)
//
#include <hip/hip_runtime.h>

#define NB 16
#define S_TOK 577
#define SP 576
#define DIM 768
#define NC 256
#define NCLS 1000
#define TK 16
#define HCH 4
#define HCHS 144  // 576/4
#define NBLK 256

typedef __attribute__((ext_vector_type(8))) __bf16 bf16x8;
typedef __attribute__((ext_vector_type(4))) float f32x4;

// ---------------- Kernel 0: split q (rows 1..576) and cw into bf16 hi/lo ----
// Also zeroes W and the grid-barrier slots.
__global__ __launch_bounds__(256) void cvt_split_k(const float* __restrict__ q,
                                                   const float* __restrict__ cw,
                                                   __bf16* __restrict__ qph,
                                                   __bf16* __restrict__ qpl,
                                                   __bf16* __restrict__ cwh,
                                                   __bf16* __restrict__ cwl,
                                                   float* __restrict__ W,
                                                   int* __restrict__ bar) {
  const int gid = blockIdx.x * 256 + threadIdx.x;
  if (gid < NB * SP) W[gid] = 0.f;
  if (gid < 8) bar[gid] = 0;
  const int QCH = NB * SP * (DIM / 8);  // 884736
  const float* src;
  __bf16 *dh, *dl;
  if (gid < QCH) {
    const int rid = gid / (DIM / 8);
    const int kc = gid % (DIM / 8);
    const int b = rid / SP, s = rid % SP;
    src = q + (((size_t)b * S_TOK + 1 + s) * DIM + kc * 8);
    dh = qph + ((size_t)rid * DIM + kc * 8);
    dl = qpl + ((size_t)rid * DIM + kc * 8);
  } else {
    const int cid = gid - QCH;  // < 24576
    src = cw + (size_t)cid * 8;
    dh = cwh + (size_t)cid * 8;
    dl = cwl + (size_t)cid * 8;
  }
  float4 v0 = *(const float4*)src;
  float4 v1 = *(const float4*)(src + 4);
  float v[8] = {v0.x, v0.y, v0.z, v0.w, v1.x, v1.y, v1.z, v1.w};
  bf16x8 h, l;
#pragma unroll
  for (int i = 0; i < 8; i++) {
    __bf16 hh = (__bf16)v[i];
    h[i] = hh;
    l[i] = (__bf16)(v[i] - (float)hh);
  }
  *(bf16x8*)dh = h;
  *(bf16x8*)dl = l;
}

// ---------------- device-scope grid barrier (256 co-resident blocks) -------
__device__ __forceinline__ void grid_barrier(int* bar, int slot) {
  __syncthreads();
  if (threadIdx.x == 0) {
    __threadfence();
    int prev = __hip_atomic_fetch_add(&bar[slot * 2], 1, __ATOMIC_ACQ_REL,
                                      __HIP_MEMORY_SCOPE_AGENT);
    if (prev == NBLK - 1) {
      __hip_atomic_store(&bar[slot * 2 + 1], 1, __ATOMIC_RELEASE,
                         __HIP_MEMORY_SCOPE_AGENT);
    } else {
      long spins = 0;
      while (__hip_atomic_load(&bar[slot * 2 + 1], __ATOMIC_ACQUIRE,
                               __HIP_MEMORY_SCOPE_AGENT) == 0) {
        __builtin_amdgcn_s_sleep(1);
        if (++spins > (1L << 22)) break;  // safety: never hit legitimately
      }
    }
    __threadfence();
  }
  __syncthreads();
}

// ---------------- Mega kernel: GEMM -> TOPK -> H -> CLS (3 grid barriers) ---
__global__ __launch_bounds__(256, 2) void mega(const float* __restrict__ q,
                                               const __bf16* __restrict__ qph,
                                               const __bf16* __restrict__ qpl,
                                               const __bf16* __restrict__ cwh,
                                               const __bf16* __restrict__ cwl,
                                               const float* __restrict__ clsw,
                                               const float* __restrict__ clsb,
                                               float* __restrict__ qk,
                                               float* __restrict__ W,
                                               float* __restrict__ hpart,
                                               float* __restrict__ y,
                                               int* __restrict__ bar) {
  __shared__ __align__(16) char smem[53248];
  const int tid = threadIdx.x;
  const int u = blockIdx.x;
  const int lane = tid & 63;
  const int wid = tid >> 6;

  // ======== P1: qk[b,c,s] = sum_d cw[c,d]*q[b,s+1,d], bf16 3-pass MFMA =====
  {
    __bf16* sAH = (__bf16*)smem;             // 64x64
    __bf16* sAL = (__bf16*)(smem + 8192);    // 64x64
    __bf16* sBH = (__bf16*)(smem + 16384);   // 144x64
    __bf16* sBL = (__bf16*)(smem + 34816);   // 144x64
    // XCD-aware mapping: all 16 (ci,si) blocks of a given b on one XCD
    // (HW round-robins dispatch index % 8 across XCDs).
    const int xcd = u & 7;
    const int slot = u >> 3;              // 0..31
    const int b = xcd * 2 + (slot >> 4);  // 2 b per XCD
    const int inner = slot & 15;
    const int ci = inner >> 2;
    const int si = inner & 3;
    const int s0 = si * 144;
    const int c0 = ci * 64;

    const int wc = wid << 4;  // wave c-offset 0/16/32/48
    const int fr = lane & 15;
    const int kqm = lane >> 4;  // k-quarter 0..3
    const int frs = fr & 7;

    const int rb = tid >> 3;  // 0..31
    const int kc = tid & 7;   // chunk in row
    const int slw = (kc ^ (rb & 7)) * 8;  // swizzled slot (bf16 elems)

    const __bf16* qbh = qph + (size_t)b * SP * DIM;
    const __bf16* qbl = qpl + (size_t)b * SP * DIM;

    f32x4 acc[9];
#pragma unroll
    for (int j = 0; j < 9; j++) acc[j] = (f32x4){0.f, 0.f, 0.f, 0.f};

    bf16x8 rAh[2], rAl[2], rBh[5], rBl[5];

#define LOADREGS(K0)                                                        \
  {                                                                         \
    const int k0_ = (K0);                                                   \
    _Pragma("unroll") for (int m = 0; m < 2; ++m) {                         \
      const size_t g = (size_t)(c0 + m * 32 + rb) * DIM + k0_ + kc * 8;     \
      rAh[m] = *(const bf16x8*)(cwh + g);                                   \
      rAl[m] = *(const bf16x8*)(cwl + g);                                   \
    }                                                                       \
    _Pragma("unroll") for (int m = 0; m < 4; ++m) {                         \
      const size_t g = (size_t)(s0 + m * 32 + rb) * DIM + k0_ + kc * 8;     \
      rBh[m] = *(const bf16x8*)(qbh + g);                                   \
      rBl[m] = *(const bf16x8*)(qbl + g);                                   \
    }                                                                       \
    if (tid < 128) {                                                        \
      const size_t g = (size_t)(s0 + 128 + rb) * DIM + k0_ + kc * 8;        \
      rBh[4] = *(const bf16x8*)(qbh + g);                                   \
      rBl[4] = *(const bf16x8*)(qbl + g);                                   \
    }                                                                       \
  }

    LOADREGS(0);
    for (int kt = 0; kt < 12; ++kt) {
      __syncthreads();
#pragma unroll
      for (int m = 0; m < 2; ++m) {
        const int r = m * 32 + rb;
        *(bf16x8*)(sAH + r * 64 + slw) = rAh[m];
        *(bf16x8*)(sAL + r * 64 + slw) = rAl[m];
      }
#pragma unroll
      for (int m = 0; m < 4; ++m) {
        const int r = m * 32 + rb;
        *(bf16x8*)(sBH + r * 64 + slw) = rBh[m];
        *(bf16x8*)(sBL + r * 64 + slw) = rBl[m];
      }
      if (tid < 128) {
        const int r = 128 + rb;
        *(bf16x8*)(sBH + r * 64 + slw) = rBh[4];
        *(bf16x8*)(sBL + r * 64 + slw) = rBl[4];
      }
      __syncthreads();
      if (kt < 11) LOADREGS((kt + 1) * 64);
#define MF(A, B, C) C = __builtin_amdgcn_mfma_f32_16x16x32_bf16(A, B, C, 0, 0, 0)
#pragma unroll
      for (int ks = 0; ks < 2; ++ks) {
        const int sl = ((ks * 4 + kqm) ^ frs) * 8;
        const bf16x8 ah = *(const bf16x8*)(sAH + (wc + fr) * 64 + sl);
        const bf16x8 al = *(const bf16x8*)(sAL + (wc + fr) * 64 + sl);
#pragma unroll
        for (int j = 0; j < 9; ++j) {
          const int br = j * 16 + fr;
          const bf16x8 bh = *(const bf16x8*)(sBH + br * 64 + sl);
          const bf16x8 bv = *(const bf16x8*)(sBL + br * 64 + sl);
          MF(ah, bh, acc[j]);
          MF(ah, bv, acc[j]);
          MF(al, bh, acc[j]);
        }
      }
#undef MF
    }
#undef LOADREGS
    // C/D layout: col(s) = lane&15, row(c) = (lane>>4)*4 + reg
    float* obase = qk + (size_t)b * NC * SP;
#pragma unroll
    for (int j = 0; j < 9; ++j)
#pragma unroll
      for (int rr = 0; rr < 4; ++rr) {
        const int row = c0 + wc + kqm * 4 + rr;
        const int col = s0 + j * 16 + fr;
        obase[(size_t)row * SP + col] = acc[j][rr];
      }
  }
  grid_barrier(bar, 0);

  // ======== P2: top-16 + softmax -> atomic scatter into W ==================
  for (int rc = u * 4 + wid; rc < NB * NC; rc += NBLK * 4) {
    const int b = rc >> 8;
    const float* rowp = qk + (size_t)rc * SP;
    float v[9];
#pragma unroll
    for (int j = 0; j < 9; j++) v[j] = rowp[lane + 64 * j];

    float vals[TK];
    int idxs[TK];
#pragma unroll
    for (int t = 0; t < TK; t++) {
      float bv = -1e30f;
      int bj = 0;
#pragma unroll
      for (int j = 0; j < 9; j++)
        if (v[j] > bv) { bv = v[j]; bj = j; }
      int bs = lane + 64 * bj;
#pragma unroll
      for (int off = 32; off >= 1; off >>= 1) {
        float ov = __shfl_xor(bv, off);
        int os = __shfl_xor(bs, off);
        if (ov > bv || (ov == bv && os < bs)) { bv = ov; bs = os; }
      }
      vals[t] = bv;
      idxs[t] = bs;
      const int clr_j = bs >> 6;
      const int clr_lane = bs & 63;
#pragma unroll
      for (int j = 0; j < 9; j++)
        if (j == clr_j && clr_lane == lane) v[j] = -1e30f;
    }
    float m = vals[0];
    float sum = 0.f;
#pragma unroll
    for (int t = 0; t < TK; t++) sum += expf(vals[t] - m);
    if (lane == 0) {
      const float inv = 1.f / (sum * (float)NC);
#pragma unroll
      for (int t = 0; t < TK; t++)
        atomicAdd(&W[b * SP + idxs[t]], expf(vals[t] - m) * inv);
    }
  }
  grid_barrier(bar, 1);

  // ======== P3: hpart[ch,b,d] = sum_{s in chunk} W[b,s]*q[b,s+1,d] =========
  if (u < 3 * NB * HCH) {  // 192 units
    float* Ws = (float*)smem;
    const int db = u % 3;
    const int rest = u / 3;
    const int b = rest % NB;
    const int ch = rest / NB;  // 0..3
    const int d = db * 256 + tid;
    if (tid < HCHS) Ws[tid] = W[b * SP + ch * HCHS + tid];
    __syncthreads();
    const float* qb = q + ((size_t)b * S_TOK + 1 + ch * HCHS) * DIM + d;
    float acc = 0.f;
#pragma unroll 8
    for (int s = 0; s < HCHS; s++) acc = fmaf(Ws[s], qb[(size_t)s * DIM], acc);
    hpart[((size_t)ch * NB + b) * DIM + d] = acc;
  }
  grid_barrier(bar, 2);

  // ======== P4: y[b,n] = relu(sum_ch hpart)[b,:] . clsw[n,:] + clsb[n] =====
  if (u < 63) {  // 16 classes per block
    float* hs = (float*)smem;  // NB*DIM floats = 48KB
    for (int i = tid; i < NB * DIM; i += 256) {
      float s = 0.f;
#pragma unroll
      for (int ch = 0; ch < HCH; ch++) s += hpart[(size_t)ch * NB * DIM + i];
      hs[i] = fmaxf(s, 0.f);
    }
    __syncthreads();
#pragma unroll
    for (int cc = 0; cc < 4; cc++) {
      const int n = u * 16 + wid * 4 + cc;
      if (n < NCLS) {
        float wr[12];
#pragma unroll
        for (int j = 0; j < 12; j++) wr[j] = clsw[(size_t)n * DIM + lane + 64 * j];
        const float bias = clsb[n];
        for (int bb = 0; bb < NB; bb++) {
          float dot = 0.f;
#pragma unroll
          for (int j = 0; j < 12; j++)
            dot = fmaf(wr[j], hs[bb * DIM + lane + 64 * j], dot);
#pragma unroll
          for (int off = 32; off >= 1; off >>= 1) dot += __shfl_xor(dot, off);
          if (lane == 0) y[bb * NCLS + n] = dot + bias;
        }
      }
    }
  }
}

extern "C" void kernel_launch(void* const* d_in, const int* in_sizes, int n_in,
                              void* d_out, int out_size, void* d_ws, size_t ws_size,
                              hipStream_t stream) {
  const float* q = (const float*)d_in[0];
  const float* cw = (const float*)d_in[1];
  const float* clsw = (const float*)d_in[2];
  const float* clsb = (const float*)d_in[3];
  float* out = (float*)d_out;

  __bf16* qph = (__bf16*)d_ws;                     // NB*SP*DIM
  __bf16* qpl = qph + (size_t)NB * SP * DIM;
  __bf16* cwh = qpl + (size_t)NB * SP * DIM;       // NC*DIM
  __bf16* cwl = cwh + (size_t)NC * DIM;
  float* W = (float*)(cwl + (size_t)NC * DIM);     // NB*SP
  float* hpart = W + (size_t)NB * SP;              // HCH*NB*DIM
  float* qk = hpart + (size_t)HCH * NB * DIM;      // NB*NC*SP
  int* bar = (int*)(qk + (size_t)NB * NC * SP);    // 8 ints

  const int CVT_BLOCKS = (NB * SP * (DIM / 8) + NC * (DIM / 8)) / 256;  // 3552
  cvt_split_k<<<CVT_BLOCKS, 256, 0, stream>>>(q, cw, qph, qpl, cwh, cwl, W, bar);
  mega<<<NBLK, 256, 0, stream>>>(q, qph, qpl, cwh, cwl, clsw, clsb, qk, W,
                                 hpart, out, bar);
}

// Round 8
// 137.811 us; speedup vs baseline: 1.5931x; 1.5931x over previous
//
#include <hip/hip_runtime.h>

#define NB 16
#define S_TOK 577
#define SP 576
#define DIM 768
#define NC 256
#define NCLS 1000
#define TK 16
#define HCH 6
#define HCHS 96  // 576/6

typedef __attribute__((ext_vector_type(8))) __bf16 bf16x8;
typedef __attribute__((ext_vector_type(4))) float f32x4;

// ---------------- Kernel 0: split q (rows 1..576) and cw into bf16 hi/lo ----
// Also zeroes W.
__global__ __launch_bounds__(256) void cvt_split_k(const float* __restrict__ q,
                                                   const float* __restrict__ cw,
                                                   __bf16* __restrict__ qph,
                                                   __bf16* __restrict__ qpl,
                                                   __bf16* __restrict__ cwh,
                                                   __bf16* __restrict__ cwl,
                                                   float* __restrict__ W) {
  const int gid = blockIdx.x * 256 + threadIdx.x;
  if (gid < NB * SP) W[gid] = 0.f;
  const int QCH = NB * SP * (DIM / 8);  // 884736
  const float* src;
  __bf16 *dh, *dl;
  if (gid < QCH) {
    const int rid = gid / (DIM / 8);
    const int kc = gid % (DIM / 8);
    const int b = rid / SP, s = rid % SP;
    src = q + (((size_t)b * S_TOK + 1 + s) * DIM + kc * 8);
    dh = qph + ((size_t)rid * DIM + kc * 8);
    dl = qpl + ((size_t)rid * DIM + kc * 8);
  } else {
    const int cid = gid - QCH;  // < 24576
    src = cw + (size_t)cid * 8;
    dh = cwh + (size_t)cid * 8;
    dl = cwl + (size_t)cid * 8;
  }
  float4 v0 = *(const float4*)src;
  float4 v1 = *(const float4*)(src + 4);
  float v[8] = {v0.x, v0.y, v0.z, v0.w, v1.x, v1.y, v1.z, v1.w};
  bf16x8 h, l;
#pragma unroll
  for (int i = 0; i < 8; i++) {
    __bf16 hh = (__bf16)v[i];
    h[i] = hh;
    l[i] = (__bf16)(v[i] - (float)hh);
  }
  *(bf16x8*)dh = h;
  *(bf16x8*)dl = l;
}

// ---------------- Kernel A: fused GEMM + top-16 + softmax + W scatter ------
// Block = (b, 16-c-row group) computing 16c x 576s. A (cw) staged in 4KB LDS
// (r6-verified swizzle); B (q hi/lo) loaded straight from L2 per wave.
// After k-loop: acc -> 36KB LDS -> per-wave top-16 -> atomicAdd into W.
__global__ __launch_bounds__(256) void gemm_topk(const __bf16* __restrict__ qph,
                                                 const __bf16* __restrict__ qpl,
                                                 const __bf16* __restrict__ cwh,
                                                 const __bf16* __restrict__ cwl,
                                                 float* __restrict__ W) {
  __shared__ __align__(16) char smem[36864];  // A-stage (4KB) then 16x576 f32
  __bf16* sAH = (__bf16*)smem;          // [16][64]
  __bf16* sAL = (__bf16*)(smem + 2048); // [16][64]
  float* tkbuf = (float*)smem;          // [16][576]

  const int tid = threadIdx.x;
  const int lane = tid & 63;
  const int wid = tid >> 6;
  // XCD-aware mapping: all 16 c-group blocks of a batch b on one XCD
  // (dispatch round-robins blockIdx % 8 across the 8 XCDs).
  const int xcd = blockIdx.x & 7;
  const int slot = blockIdx.x >> 3;     // 0..31
  const int b = xcd * 2 + (slot >> 4);  // 2 b per XCD
  const int c0 = (slot & 15) * 16;

  const int fr = lane & 15;
  const int kqm = lane >> 4;  // k-chunk-in-32 quarter
  const int frs = fr & 7;
  const int s0w = wid * 144;

  const __bf16* qbh = qph + (size_t)b * SP * DIM;
  const __bf16* qbl = qpl + (size_t)b * SP * DIM;

  // A staging assignment: one bf16x8 per thread. t<128 -> hi, else lo.
  const int ar = (tid & 127) >> 3;   // row 0..15
  const int akc = tid & 7;           // chunk 0..7
  const int aslot = ar * 64 + ((akc ^ (ar & 7)) * 8);  // elems
  const __bf16* asrc_base = (tid < 128 ? cwh : cwl) + (size_t)(c0 + ar) * DIM + akc * 8;
  __bf16* adst = (tid < 128 ? sAH : sAL) + aslot;

  f32x4 acc[9];
#pragma unroll
  for (int j = 0; j < 9; j++) acc[j] = (f32x4){0.f, 0.f, 0.f, 0.f};

  bf16x8 c0h[9], c0l[9], n0h[9], n0l[9];

#define LOADB(DH, DL, KT, KS)                                          \
  {                                                                    \
    const size_t koff = (size_t)(KT) * 64 + (KS) * 32 + kqm * 8;       \
    _Pragma("unroll") for (int j = 0; j < 9; ++j) {                    \
      const size_t g = (size_t)(s0w + j * 16 + fr) * DIM + koff;       \
      DH[j] = *(const bf16x8*)(qbh + g);                               \
      DL[j] = *(const bf16x8*)(qbl + g);                               \
    }                                                                  \
  }

#define MF(A, B, C) C = __builtin_amdgcn_mfma_f32_16x16x32_bf16(A, B, C, 0, 0, 0)

  LOADB(c0h, c0l, 0, 0);
  for (int kt = 0; kt < 12; ++kt) {
    __syncthreads();  // previous iter's A readers done
    *(bf16x8*)adst = *(const bf16x8*)(asrc_base + kt * 64);
    __syncthreads();  // A ready
    // ---- ks = 0 ----
    LOADB(n0h, n0l, kt, 1);  // prefetch second half
    {
      const int sl = ((kqm) ^ frs) * 8;
      const bf16x8 ah = *(const bf16x8*)(sAH + fr * 64 + sl);
      const bf16x8 al = *(const bf16x8*)(sAL + fr * 64 + sl);
#pragma unroll
      for (int j = 0; j < 9; ++j) {
        MF(ah, c0h[j], acc[j]);
        MF(ah, c0l[j], acc[j]);
        MF(al, c0h[j], acc[j]);
      }
    }
    // ---- ks = 1 ----
    if (kt < 11) LOADB(c0h, c0l, kt + 1, 0);  // prefetch next tile 1st half
    {
      const int sl = ((4 + kqm) ^ frs) * 8;
      const bf16x8 ah = *(const bf16x8*)(sAH + fr * 64 + sl);
      const bf16x8 al = *(const bf16x8*)(sAL + fr * 64 + sl);
#pragma unroll
      for (int j = 0; j < 9; ++j) {
        MF(ah, n0h[j], acc[j]);
        MF(ah, n0l[j], acc[j]);
        MF(al, n0h[j], acc[j]);
      }
    }
  }
#undef MF
#undef LOADB

  // ---- acc -> LDS [16][576]: row(c)= kqm*4+rr, col(s)= s0w + j*16 + fr ----
  __syncthreads();  // all A reads done before overwriting smem
#pragma unroll
  for (int j = 0; j < 9; ++j)
#pragma unroll
    for (int rr = 0; rr < 4; ++rr)
      tkbuf[(kqm * 4 + rr) * 576 + s0w + j * 16 + fr] = acc[j][rr];
  __syncthreads();

  // ---- per-wave top-16 over 4 rows each ----
  for (int i = 0; i < 4; ++i) {
    const int row = wid * 4 + i;
    const float* rowp = tkbuf + row * 576;
    float v[9];
#pragma unroll
    for (int j = 0; j < 9; j++) v[j] = rowp[lane + 64 * j];

    float vals[TK];
    int idxs[TK];
#pragma unroll
    for (int t = 0; t < TK; t++) {
      float bv = -1e30f;
      int bj = 0;
#pragma unroll
      for (int j = 0; j < 9; j++)
        if (v[j] > bv) { bv = v[j]; bj = j; }
      int bs = lane + 64 * bj;
#pragma unroll
      for (int off = 32; off >= 1; off >>= 1) {
        float ov = __shfl_xor(bv, off);
        int os = __shfl_xor(bs, off);
        if (ov > bv || (ov == bv && os < bs)) { bv = ov; bs = os; }
      }
      vals[t] = bv;
      idxs[t] = bs;
      const int clr_j = bs >> 6;
      const int clr_lane = bs & 63;
#pragma unroll
      for (int j = 0; j < 9; j++)
        if (j == clr_j && clr_lane == lane) v[j] = -1e30f;
    }
    float m = vals[0];
    float sum = 0.f;
#pragma unroll
    for (int t = 0; t < TK; t++) sum += expf(vals[t] - m);
    if (lane == 0) {
      const float inv = 1.f / (sum * (float)NC);
#pragma unroll
      for (int t = 0; t < TK; t++)
        atomicAdd(&W[b * SP + idxs[t]], expf(vals[t] - m) * inv);
    }
  }
}

// ---------------- Kernel B: hpart[ch,b,d] = sum_{s in chunk} W*q ------------
__global__ __launch_bounds__(256) void h_partial(const float* __restrict__ q,
                                                 const float* __restrict__ W,
                                                 float* __restrict__ hpart) {
  const int b = blockIdx.y;
  const int ch = blockIdx.z;
  const int d = blockIdx.x * 256 + threadIdx.x;
  __shared__ float Ws[HCHS];
  if (threadIdx.x < HCHS) Ws[threadIdx.x] = W[b * SP + ch * HCHS + threadIdx.x];
  __syncthreads();
  const float* qb = q + ((size_t)b * S_TOK + 1 + ch * HCHS) * DIM + d;
  float acc = 0.f;
#pragma unroll 8
  for (int s = 0; s < HCHS; s++) acc = fmaf(Ws[s], qb[(size_t)s * DIM], acc);
  hpart[((size_t)ch * NB + b) * DIM + d] = acc;
}

// ---------------- Kernel C: y = relu(sum_ch hpart) @ cls_w^T + cls_b --------
__global__ __launch_bounds__(256) void cls_head(const float* __restrict__ hp,
                                                const float* __restrict__ cw,
                                                const float* __restrict__ cb,
                                                float* __restrict__ y) {
  __shared__ float hs[NB * DIM];
  for (int i = threadIdx.x; i < NB * DIM; i += 256) {
    float s = 0.f;
#pragma unroll
    for (int ch = 0; ch < HCH; ch++) s += hp[(size_t)ch * NB * DIM + i];
    hs[i] = fmaxf(s, 0.f);
  }
  __syncthreads();
  const int lane = threadIdx.x & 63;
  const int n = blockIdx.x * 4 + (threadIdx.x >> 6);
  float wr[12];
#pragma unroll
  for (int j = 0; j < 12; j++) wr[j] = cw[(size_t)n * DIM + lane + 64 * j];
  const float bias = cb[n];
  for (int bb = 0; bb < NB; bb++) {
    float dot = 0.f;
#pragma unroll
    for (int j = 0; j < 12; j++)
      dot = fmaf(wr[j], hs[bb * DIM + lane + 64 * j], dot);
#pragma unroll
    for (int off = 32; off >= 1; off >>= 1) dot += __shfl_xor(dot, off);
    if (lane == 0) y[bb * NCLS + n] = dot + bias;
  }
}

extern "C" void kernel_launch(void* const* d_in, const int* in_sizes, int n_in,
                              void* d_out, int out_size, void* d_ws, size_t ws_size,
                              hipStream_t stream) {
  const float* q = (const float*)d_in[0];
  const float* cw = (const float*)d_in[1];
  const float* clsw = (const float*)d_in[2];
  const float* clsb = (const float*)d_in[3];
  float* out = (float*)d_out;

  __bf16* qph = (__bf16*)d_ws;                     // NB*SP*DIM
  __bf16* qpl = qph + (size_t)NB * SP * DIM;
  __bf16* cwh = qpl + (size_t)NB * SP * DIM;       // NC*DIM
  __bf16* cwl = cwh + (size_t)NC * DIM;
  float* W = (float*)(cwl + (size_t)NC * DIM);     // NB*SP
  float* hpart = W + (size_t)NB * SP;              // HCH*NB*DIM

  const int CVT_BLOCKS = (NB * SP * (DIM / 8) + NC * (DIM / 8)) / 256;  // 3552
  cvt_split_k<<<CVT_BLOCKS, 256, 0, stream>>>(q, cw, qph, qpl, cwh, cwl, W);
  gemm_topk<<<NB * 16, 256, 0, stream>>>(qph, qpl, cwh, cwl, W);
  h_partial<<<dim3(3, NB, HCH), 256, 0, stream>>>(q, W, hpart);
  cls_head<<<NCLS / 4, 256, 0, stream>>>(hpart, clsw, clsb, out);
}

// Round 9
// 133.517 us; speedup vs baseline: 1.6444x; 1.0322x over previous
//
#include <hip/hip_runtime.h>

#define NB 16
#define S_TOK 577
#define SP 576
#define DIM 768
#define NC 256
#define NCLS 1000
#define TK 16
#define HCH 8
#define HCHS 72   // 576/8
#define NSEG 3
#define SEG 192   // 576/3

typedef __attribute__((ext_vector_type(8))) __bf16 bf16x8;
typedef __attribute__((ext_vector_type(4))) float f32x4;

// ---------------- Kernel 0: split q (rows 1..576) and cw into bf16 hi/lo ----
// Also zeroes W.
__global__ __launch_bounds__(256) void cvt_split_k(const float* __restrict__ q,
                                                   const float* __restrict__ cw,
                                                   __bf16* __restrict__ qph,
                                                   __bf16* __restrict__ qpl,
                                                   __bf16* __restrict__ cwh,
                                                   __bf16* __restrict__ cwl,
                                                   float* __restrict__ W) {
  const int gid = blockIdx.x * 256 + threadIdx.x;
  if (gid < NB * SP) W[gid] = 0.f;
  const int QCH = NB * SP * (DIM / 8);  // 884736
  const float* src;
  __bf16 *dh, *dl;
  if (gid < QCH) {
    const int rid = gid / (DIM / 8);
    const int kc = gid % (DIM / 8);
    const int b = rid / SP, s = rid % SP;
    src = q + (((size_t)b * S_TOK + 1 + s) * DIM + kc * 8);
    dh = qph + ((size_t)rid * DIM + kc * 8);
    dl = qpl + ((size_t)rid * DIM + kc * 8);
  } else {
    const int cid = gid - QCH;  // < 24576
    src = cw + (size_t)cid * 8;
    dh = cwh + (size_t)cid * 8;
    dl = cwl + (size_t)cid * 8;
  }
  float4 v0 = *(const float4*)src;
  float4 v1 = *(const float4*)(src + 4);
  float v[8] = {v0.x, v0.y, v0.z, v0.w, v1.x, v1.y, v1.z, v1.w};
  bf16x8 h, l;
#pragma unroll
  for (int i = 0; i < 8; i++) {
    __bf16 hh = (__bf16)v[i];
    h[i] = hh;
    l[i] = (__bf16)(v[i] - (float)hh);
  }
  *(bf16x8*)dh = h;
  *(bf16x8*)dl = l;
}

// ---------------- Kernel A: GEMM + per-segment top-16 candidates -----------
// Block = (b, 16-c group, 192-s segment); 384 threads / 6 waves, wave owns
// 2 s-tiles. A (cwh/cwl) staged in 4KB LDS (R8-validated swizzle); B read
// per-wave from L2. 768 blocks = 3/CU.
__global__ __launch_bounds__(384) void gemm_topk_part(
    const __bf16* __restrict__ qph, const __bf16* __restrict__ qpl,
    const __bf16* __restrict__ cwh, const __bf16* __restrict__ cwl,
    float* __restrict__ cand, int* __restrict__ candi) {
  __shared__ __align__(16) char smem[12288];  // A-stage 4KB, then 16x192 f32
  __bf16* sAH = (__bf16*)smem;           // [16][64]
  __bf16* sAL = (__bf16*)(smem + 2048);  // [16][64]
  float* tkbuf = (float*)smem;           // [16][192]

  const int tid = threadIdx.x;
  const int lane = tid & 63;
  const int wid = tid >> 6;  // 0..5
  // XCD swizzle: 48 blocks (16 cgrp x 3 seg) of each b land on one XCD.
  const int xcd = blockIdx.x & 7;
  const int slot = blockIdx.x >> 3;  // 0..95
  const int half = (slot >= 48) ? 1 : 0;
  const int b = xcd * 2 + half;
  const int inner = slot - half * 48;  // 0..47
  const int cg = inner / NSEG;
  const int seg = inner % NSEG;
  const int c0 = cg * 16;

  const int fr = lane & 15;
  const int kqm = lane >> 4;  // k-chunk quarter 0..3
  const int frs = fr & 7;
  const int s0w = seg * SEG + wid * 32;

  const __bf16* qbh = qph + (size_t)b * SP * DIM;
  const __bf16* qbl = qpl + (size_t)b * SP * DIM;

  // A staging: one bf16x8/thread, t<128 -> hi, 128<=t<256 -> lo.
  const int ar = (tid & 127) >> 3;  // row 0..15
  const int akc = tid & 7;          // chunk 0..7
  const int aslot = ar * 64 + ((akc ^ (ar & 7)) * 8);
  const __bf16* asrc = (tid < 128 ? cwh : cwl) + (size_t)(c0 + ar) * DIM + akc * 8;
  __bf16* adst = (tid < 128 ? sAH : sAL) + aslot;

  f32x4 acc[2];
  acc[0] = (f32x4){0.f, 0.f, 0.f, 0.f};
  acc[1] = (f32x4){0.f, 0.f, 0.f, 0.f};

  bf16x8 cbh[2], cbl[2], nbh[2], nbl[2];

#define LOADB(DH, DL, KT, KS)                                            \
  {                                                                      \
    const size_t koff = (size_t)(KT) * 64 + (KS) * 32 + kqm * 8;         \
    _Pragma("unroll") for (int jj = 0; jj < 2; ++jj) {                   \
      const size_t g = (size_t)(s0w + jj * 16 + fr) * DIM + koff;        \
      DH[jj] = *(const bf16x8*)(qbh + g);                                \
      DL[jj] = *(const bf16x8*)(qbl + g);                                \
    }                                                                    \
  }
#define MF(A, B, C) C = __builtin_amdgcn_mfma_f32_16x16x32_bf16(A, B, C, 0, 0, 0)

  LOADB(cbh, cbl, 0, 0);
  for (int kt = 0; kt < 12; ++kt) {
    __syncthreads();  // previous iter's A readers done
    if (tid < 256) *(bf16x8*)adst = *(const bf16x8*)(asrc + kt * 64);
    __syncthreads();  // A ready
    LOADB(nbh, nbl, kt, 1);  // prefetch ks=1 while ks=0 computes
    {
      const int sl = (kqm ^ frs) * 8;
      const bf16x8 ah = *(const bf16x8*)(sAH + fr * 64 + sl);
      const bf16x8 al = *(const bf16x8*)(sAL + fr * 64 + sl);
#pragma unroll
      for (int jj = 0; jj < 2; ++jj) {
        MF(ah, cbh[jj], acc[jj]);
        MF(ah, cbl[jj], acc[jj]);
        MF(al, cbh[jj], acc[jj]);
      }
    }
    if (kt < 11) LOADB(cbh, cbl, kt + 1, 0);  // prefetch next tile ks=0
    {
      const int sl = ((4 + kqm) ^ frs) * 8;
      const bf16x8 ah = *(const bf16x8*)(sAH + fr * 64 + sl);
      const bf16x8 al = *(const bf16x8*)(sAL + fr * 64 + sl);
#pragma unroll
      for (int jj = 0; jj < 2; ++jj) {
        MF(ah, nbh[jj], acc[jj]);
        MF(ah, nbl[jj], acc[jj]);
        MF(al, nbh[jj], acc[jj]);
      }
    }
  }
#undef MF
#undef LOADB

  // acc -> LDS [16][192]: row(c)=kqm*4+rr, col(s-local)=wid*32+jj*16+fr
  __syncthreads();
#pragma unroll
  for (int jj = 0; jj < 2; ++jj)
#pragma unroll
    for (int rr = 0; rr < 4; ++rr)
      tkbuf[(kqm * 4 + rr) * SEG + wid * 32 + jj * 16 + fr] = acc[jj][rr];
  __syncthreads();

  // per-wave top-16 of this 192-s segment (rows wid, wid+6, wid+12)
  for (int r = wid; r < 16; r += 6) {
    const float* rowp = tkbuf + r * SEG;
    float v[3];
#pragma unroll
    for (int j = 0; j < 3; j++) v[j] = rowp[lane + 64 * j];
    const size_t obase = ((size_t)(b * NC + c0 + r)) * (NSEG * TK) + seg * TK;
    for (int t = 0; t < TK; t++) {
      float bv = -1e30f;
      int bj = 0;
#pragma unroll
      for (int j = 0; j < 3; j++)
        if (v[j] > bv) { bv = v[j]; bj = j; }
      int bs = lane + 64 * bj;
#pragma unroll
      for (int off = 32; off >= 1; off >>= 1) {
        float ov = __shfl_xor(bv, off);
        int os = __shfl_xor(bs, off);
        if (ov > bv || (ov == bv && os < bs)) { bv = ov; bs = os; }
      }
      if (lane == 0) {
        cand[obase + t] = bv;
        candi[obase + t] = seg * SEG + bs;
      }
      const int cj = bs >> 6;
      const int cl = bs & 63;
#pragma unroll
      for (int j = 0; j < 3; j++)
        if (j == cj && cl == lane) v[j] = -1e30f;
    }
  }
}

// ---------------- Kernel B: merge 48 candidates -> top-16, softmax, scatter
__global__ __launch_bounds__(256) void merge_scatter(const float* __restrict__ cand,
                                                     const int* __restrict__ candi,
                                                     float* __restrict__ W) {
  const int lane = threadIdx.x & 63;
  const int wid = threadIdx.x >> 6;
  const int rc = blockIdx.x * 4 + wid;  // 0..4095
  const int b = rc >> 8;
  float cv = -1e30f;
  int ci = 0x7fffffff;
  if (lane < NSEG * TK) {
    cv = cand[(size_t)rc * (NSEG * TK) + lane];
    ci = candi[(size_t)rc * (NSEG * TK) + lane];
  }
  float vals[TK];
  int idxs[TK];
#pragma unroll
  for (int t = 0; t < TK; t++) {
    float bv = cv;
    int bi = ci;
#pragma unroll
    for (int off = 32; off >= 1; off >>= 1) {
      float ov = __shfl_xor(bv, off);
      int oi = __shfl_xor(bi, off);
      if (ov > bv || (ov == bv && oi < bi)) { bv = ov; bi = oi; }
    }
    vals[t] = bv;
    idxs[t] = bi;
    if (bi == ci) cv = -1e30f;  // owner lane retires its candidate
  }
  float m = vals[0];
  float sum = 0.f;
#pragma unroll
  for (int t = 0; t < TK; t++) sum += expf(vals[t] - m);
  if (lane == 0) {
    const float inv = 1.f / (sum * (float)NC);
#pragma unroll
    for (int t = 0; t < TK; t++)
      atomicAdd(&W[b * SP + idxs[t]], expf(vals[t] - m) * inv);
  }
}

// ---------------- Kernel C: hpart[ch,b,d] = sum_{s in chunk} W*q ------------
__global__ __launch_bounds__(256) void h_partial(const float* __restrict__ q,
                                                 const float* __restrict__ W,
                                                 float* __restrict__ hpart) {
  const int b = blockIdx.y;
  const int ch = blockIdx.z;
  const int d = blockIdx.x * 256 + threadIdx.x;
  __shared__ float Ws[HCHS];
  if (threadIdx.x < HCHS) Ws[threadIdx.x] = W[b * SP + ch * HCHS + threadIdx.x];
  __syncthreads();
  const float* qb = q + ((size_t)b * S_TOK + 1 + ch * HCHS) * DIM + d;
  float acc = 0.f;
#pragma unroll 8
  for (int s = 0; s < HCHS; s++) acc = fmaf(Ws[s], qb[(size_t)s * DIM], acc);
  hpart[((size_t)ch * NB + b) * DIM + d] = acc;
}

// ---------------- Kernel D: y = relu(sum_ch hpart) @ cls_w^T + cls_b --------
__global__ __launch_bounds__(256) void cls_head(const float* __restrict__ hp,
                                                const float* __restrict__ cw,
                                                const float* __restrict__ cb,
                                                float* __restrict__ y) {
  __shared__ float hs[NB * DIM];
  for (int i = threadIdx.x; i < NB * DIM; i += 256) {
    float s = 0.f;
#pragma unroll
    for (int ch = 0; ch < HCH; ch++) s += hp[(size_t)ch * NB * DIM + i];
    hs[i] = fmaxf(s, 0.f);
  }
  __syncthreads();
  const int lane = threadIdx.x & 63;
  const int n = blockIdx.x * 4 + (threadIdx.x >> 6);
  float wr[12];
#pragma unroll
  for (int j = 0; j < 12; j++) wr[j] = cw[(size_t)n * DIM + lane + 64 * j];
  const float bias = cb[n];
  for (int bb = 0; bb < NB; bb++) {
    float dot = 0.f;
#pragma unroll
    for (int j = 0; j < 12; j++)
      dot = fmaf(wr[j], hs[bb * DIM + lane + 64 * j], dot);
#pragma unroll
    for (int off = 32; off >= 1; off >>= 1) dot += __shfl_xor(dot, off);
    if (lane == 0) y[bb * NCLS + n] = dot + bias;
  }
}

extern "C" void kernel_launch(void* const* d_in, const int* in_sizes, int n_in,
                              void* d_out, int out_size, void* d_ws, size_t ws_size,
                              hipStream_t stream) {
  const float* q = (const float*)d_in[0];
  const float* cw = (const float*)d_in[1];
  const float* clsw = (const float*)d_in[2];
  const float* clsb = (const float*)d_in[3];
  float* out = (float*)d_out;

  __bf16* qph = (__bf16*)d_ws;                      // NB*SP*DIM
  __bf16* qpl = qph + (size_t)NB * SP * DIM;
  __bf16* cwh = qpl + (size_t)NB * SP * DIM;        // NC*DIM
  __bf16* cwl = cwh + (size_t)NC * DIM;
  float* W = (float*)(cwl + (size_t)NC * DIM);      // NB*SP
  float* hpart = W + (size_t)NB * SP;               // HCH*NB*DIM
  float* cand = hpart + (size_t)HCH * NB * DIM;     // NB*NC*NSEG*TK
  int* candi = (int*)(cand + (size_t)NB * NC * NSEG * TK);

  const int CVT_BLOCKS = (NB * SP * (DIM / 8) + NC * (DIM / 8)) / 256;  // 3552
  cvt_split_k<<<CVT_BLOCKS, 256, 0, stream>>>(q, cw, qph, qpl, cwh, cwl, W);
  gemm_topk_part<<<NB * 16 * NSEG, 384, 0, stream>>>(qph, qpl, cwh, cwl, cand, candi);
  merge_scatter<<<(NB * NC) / 4, 256, 0, stream>>>(cand, candi, W);
  h_partial<<<dim3(3, NB, HCH), 256, 0, stream>>>(q, W, hpart);
  cls_head<<<NCLS / 4, 256, 0, stream>>>(hpart, clsw, clsb, out);
}